// Round 9
// baseline (129.861 us; speedup 1.0000x reference)
//
#include <hip/hip_runtime.h>
#include <math.h>

constexpr int Dn = 4096;     // C*H*W (row length)
constexpr int Bn = 4096;     // batch
constexpr int NCLS = 10;
constexpr int CH = 8;        // rows per chunk == waves per pass12 block
constexpr int NBLK0 = Bn / 256;         // 16 pass0 blocks
constexpr int MAXCH = Bn / CH + NCLS;   // 522 grid upper bound

// Workspace layout (float/int units). NO pre-zeroing needed:
// every slot is written exactly once by plain stores before being read.
constexpr int OFF_CEB  = 0;      // 16 floats: per-block CE sums
constexpr int OFF_CNT  = 16;     // 16*10 ints: blkcnt[b][c]
constexpr int OFF_XS   = 176;    // 1 float (zeroed by pass0 block 0)
constexpr int OFF_DONE = 177;    // 1 int   (zeroed by pass0 block 0)
constexpr int OFF_ORDB = 192;    // 16*10*256 ints: ORDB[b][c][r]
constexpr int OFF_P    = 41216;  // partials: MAXCH * 4096 floats (16B aligned)

// ---------------------------------------------------------------- pass 0
// CE + argmax + block-local class lists. 16 blocks x 256. NO global atomics.
__global__ __launch_bounds__(256) void pass0_ce_order(
    const float* __restrict__ outputs, const int* __restrict__ y,
    float* __restrict__ ws)
{
    const int t = threadIdx.x;
    const int b = blockIdx.x;
    const int i = b * 256 + t;
    const int w = t >> 6, lane = t & 63;
    int* wsi = (int*)ws;

    __shared__ int hist[NCLS];
    __shared__ float sce[4];
    if (t < NCLS) hist[t] = 0;
    __syncthreads();

    const float* o = outputs + (size_t)i * NCLS;
    float m = o[0]; int am = 0;
    #pragma unroll
    for (int k = 1; k < NCLS; ++k) { float ok = o[k]; if (ok > m) { m = ok; am = k; } }
    float se = 0.f;
    #pragma unroll
    for (int k = 0; k < NCLS; ++k) se += expf(o[k] - m);
    float ce = m + logf(se) - o[y[i]];

    int rank = atomicAdd(&hist[am], 1);              // LDS atomic only (tiny)
    wsi[OFF_ORDB + (b * NCLS + am) * 256 + rank] = i;

    #pragma unroll
    for (int off = 32; off; off >>= 1) ce += __shfl_down(ce, off, 64);
    if (lane == 0) sce[w] = ce;
    __syncthreads();

    if (t < NCLS) wsi[OFF_CNT + b * NCLS + t] = hist[t];
    if (t == 0) ws[OFF_CEB + b] = sce[0] + sce[1] + sce[2] + sce[3];
    if (b == 0 && t == 32) { ws[OFF_XS] = 0.f; wsi[OFF_DONE] = 0; }
}

// ---------------------------------------------------------------- pass 12
// Round-9 design: STAGE NOTHING. Ledger: LDS atomics banned (R1/2/5/6:
// >=138us); LDS row-staging + phase barriers = R7/R8, ~8us worse than R0;
// grad re-reads are L3-absorbed (R0/R5: FETCH ~33MB despite 3 passes).
// So: stats pass streams each row once from HBM (moment identity, exact
// per R6-R8), publishes (idx, a, b) per row; ONE barrier; combine re-reads
// the 8 rows straight from L2/L3, branch-free (tail rows get a=b=0 and
// row 0 as dummy: fmaf(g,0,acc)==acc exactly). LDS ~1KB, no phases.
__global__ __launch_bounds__(512, 4) void pass12_fused(
    const float* __restrict__ grad, float* __restrict__ ws)
{
    const int* wsi = (const int*)ws;
    const int t = threadIdx.x, w = t >> 6, lane = t & 63;

    __shared__ int lcnt[NBLK0 * NCLS];   // blkcnt[b][c]
    __shared__ int tot[NCLS];
    __shared__ int idx8[CH];
    __shared__ float A8[CH], B8[CH];

    if (t < NBLK0 * NCLS) lcnt[t] = wsi[OFF_CNT + t];
    __syncthreads();
    if (t < NCLS) {
        int s = 0;
        #pragma unroll
        for (int bb = 0; bb < NBLK0; ++bb) s += lcnt[bb * NCLS + t];
        tot[t] = s;
    }
    __syncthreads();

    // chunk map: blockIdx.x -> (class c, global start s0, class count cnt)
    int c = -1, s0 = 0, cnt = 0;
    {
        int bidx = (int)blockIdx.x, acc = 0;
        #pragma unroll
        for (int k = 0; k < NCLS; ++k) {
            int n = tot[k];
            int nch = (n + CH - 1) / CH;
            if (c < 0 && bidx < acc + nch) { c = k; s0 = (bidx - acc) * CH; cnt = n; }
            acc += nch;
        }
    }
    if (c < 0) return;                   // block-uniform, after all barriers
    const int m = min(CH, cnt - s0);     // >=1 for any active block

    if (w < m) {
        // map class-rank r -> source pass0 block + local pos
        int idx;
        {
            const int r = s0 + w;
            int pref = 0, src = 0, loc = 0;
            #pragma unroll
            for (int bb = 0; bb < NBLK0; ++bb) {
                int n = lcnt[bb * NCLS + c];
                if (r >= pref && r < pref + n) { src = bb; loc = r - pref; }
                pref += n;
            }
            idx = wsi[OFF_ORDB + (src * NCLS + c) * 256 + loc];
        }
        const float4* row = (const float4*)grad + (size_t)idx * (Dn / 4);

        // single stats stream: (min, sum, sumsq); nothing staged, nothing live
        float mn = 3.4e38f, sg = 0.f, sg2 = 0.f;
        #pragma unroll
        for (int k = 0; k < 16; ++k) {
            float4 v = row[k * 64 + lane];
            mn = fminf(mn, fminf(fminf(v.x, v.y), fminf(v.z, v.w)));
            sg += (v.x + v.y) + (v.z + v.w);
            sg2 = fmaf(v.x, v.x, fmaf(v.y, v.y, fmaf(v.z, v.z, fmaf(v.w, v.w, sg2))));
        }
        #pragma unroll
        for (int off = 1; off < 64; off <<= 1) {
            mn  = fminf(mn, __shfl_xor(mn, off, 64));
            sg  += __shfl_xor(sg, off, 64);
            sg2 += __shfl_xor(sg2, off, 64);
        }
        if (lane == 0) {
            // ss = sum(g-mn)^2 via moment identity (verified exact R6-R8)
            const float ss = fmaf(mn, fmaf((float)Dn, mn, -2.f * sg), sg2);
            const float a = 1.0f / sqrtf(ss);   // min-max range cancels under L2
            idx8[w] = idx; A8[w] = a; B8[w] = -mn * a;
        }
    } else if (lane == 0) {
        idx8[w] = 0; A8[w] = 0.f; B8[w] = 0.f;   // inert row: fmaf(g,0,acc)==acc
    }
    __syncthreads();

    // combine: re-read the 8 rows from L2/L3 (just streamed by this block),
    // branch-free full unroll. Thread t owns float4-quads t and t+512.
    float sb = 0.f;
    #pragma unroll
    for (int r = 0; r < CH; ++r) sb += B8[r];

    const float4* R[CH];
    #pragma unroll
    for (int r = 0; r < CH; ++r)
        R[r] = (const float4*)grad + (size_t)idx8[r] * (Dn / 4);

    float4* Pc = (float4*)(ws + OFF_P) + (size_t)blockIdx.x * (Dn / 4);
    #pragma unroll
    for (int i = 0; i < 2; ++i) {
        const int q = t + 512 * i;
        float ox = sb, oy = sb, oz = sb, ow = sb;
        #pragma unroll
        for (int r = 0; r < CH; ++r) {
            float4 u = R[r][q];
            const float a = A8[r];
            ox = fmaf(u.x, a, ox); oy = fmaf(u.y, a, oy);
            oz = fmaf(u.z, a, oz); ow = fmaf(u.w, a, ow);
        }
        Pc[q] = make_float4(ox, oy, oz, ow);
    }
}

// ---------------------------------------------------------------- pass 34
// Reduce chunk partials per class (~52 chunks/class, 8.6 MB total, freshly
// written -> L2/L3-warm), square, sum; last block finalizes. 64-thread
// blocks, grid 640: spreads the latency-bound chunk loop over all CUs with
// ~52 independent loads/thread of ILP.
__global__ __launch_bounds__(64) void pass34_final(
    float* __restrict__ ws, float* __restrict__ out)
{
    const int t = threadIdx.x;
    const int idx = blockIdx.x * 64 + t;     // 0 .. 40959
    const int c = idx >> 12;                 // class (uniform per block)
    const int j = idx & (Dn - 1);
    const int* wsi = (const int*)ws;

    __shared__ int tot[NCLS];
    if (t < NCLS) {
        int s = 0;
        #pragma unroll
        for (int bb = 0; bb < NBLK0; ++bb) s += wsi[OFF_CNT + bb * NCLS + t];
        tot[t] = s;
    }
    __syncthreads();

    int cs = 0, ce2 = 0;
    {
        int acc = 0;
        #pragma unroll
        for (int k = 0; k < NCLS; ++k) {
            int nch = (tot[k] + CH - 1) / CH;
            if (k == c) { cs = acc; ce2 = acc + nch; }
            acc += nch;
        }
    }

    const float* P = ws + OFF_P;
    float s = 0.f;
    int ch = cs;
    for (; ch + 4 <= ce2; ch += 4)
        s += P[(size_t)(ch + 0) * Dn + j] + P[(size_t)(ch + 1) * Dn + j]
           + P[(size_t)(ch + 2) * Dn + j] + P[(size_t)(ch + 3) * Dn + j];
    for (; ch < ce2; ++ch) s += P[(size_t)ch * Dn + j];
    float p = s * s;

    #pragma unroll
    for (int off = 32; off; off >>= 1) p += __shfl_down(p, off, 64);
    if (t == 0) {
        atomicAdd(&ws[OFF_XS], p);
        __threadfence();
        int ticket = atomicAdd(&((int*)ws)[OFF_DONE], 1);
        if (ticket == (NCLS * Dn / 64) - 1) {
            float xs = atomicAdd(&ws[OFF_XS], 0.0f);   // coherent read
            double n2 = 0.0;
            #pragma unroll
            for (int k = 0; k < NCLS; ++k) { double nc = (double)tot[k]; n2 += nc * nc; }
            double cesum = 0.0;
            #pragma unroll
            for (int k = 0; k < NBLK0; ++k) cesum += (double)ws[OFF_CEB + k];
            double xloss = (n2 - (double)xs) / (2.0 * (double)Bn);
            out[0] = (float)(cesum / (double)Bn + xloss);
        }
    }
}

extern "C" void kernel_launch(void* const* d_in, const int* in_sizes, int n_in,
                              void* d_out, int out_size, void* d_ws, size_t ws_size,
                              hipStream_t stream)
{
    const float* outputs = (const float*)d_in[0];   // [4096,10] f32
    const float* grad    = (const float*)d_in[1];   // [4096,1,64,64] f32
    const int*   y       = (const int*)d_in[2];     // [4096] i32
    float* ws  = (float*)d_ws;
    float* out = (float*)d_out;

    pass0_ce_order<<<NBLK0, 256, 0, stream>>>(outputs, y, ws);
    pass12_fused<<<MAXCH, 512, 0, stream>>>(grad, ws);
    pass34_final<<<NCLS * Dn / 64, 64, 0, stream>>>(ws, out);
}